// Round 1
// baseline (172.463 us; speedup 1.0000x reference)
//
#include <hip/hip_runtime.h>
#include <cstdint>

typedef _Float16 f16x8 __attribute__((ext_vector_type(8)));
typedef _Float16 f16x4 __attribute__((ext_vector_type(4)));
typedef float    f32x4 __attribute__((ext_vector_type(4)));

static constexpr int TB = 2;
static constexpr int TT = 2048;
static constexpr int TE = 768;
static constexpr int TH = 12;
static constexpr int TD = 64;
static constexpr int TM = TB * TT;      // 4096 rows (B*T)
static constexpr int TK = TE;           // 768 (K for both GEMMs)
static constexpr int NQKV = 3 * TE;     // 2304

#define SCALE_LOG2E 0.18033688011112042f  /* (1/sqrt(64)) * log2(e) */

// async global->LDS, 16B per lane. LDS dest is wave-uniform base + lane*16.
__device__ __forceinline__ void gload16(const void* g, void* lds) {
  __builtin_amdgcn_global_load_lds(
      (__attribute__((address_space(1))) void*)(uintptr_t)g,
      (__attribute__((address_space(3))) void*)(uint32_t)(uintptr_t)lds, 16, 0, 0);
}

// ---------------------------------------------------------------------------
// f32 -> f16 convert for x, w_qkv, w_final (4 elems/thread)
// ---------------------------------------------------------------------------
__global__ void cvt3(const float* __restrict__ x, const float* __restrict__ wq,
                     const float* __restrict__ wf, _Float16* __restrict__ xh,
                     _Float16* __restrict__ wqh, _Float16* __restrict__ wfh) {
  const int NX = TM * TK / 4, NW = NQKV * TK / 4, NF = TE * TE / 4;
  int i = blockIdx.x * 256 + threadIdx.x;
  const float4* src; _Float16* dst; int j;
  if (i < NX)            { src = (const float4*)x;  dst = xh;  j = i; }
  else if (i < NX + NW)  { src = (const float4*)wq; dst = wqh; j = i - NX; }
  else                   { src = (const float4*)wf; dst = wfh; j = i - NX - NW; }
  float4 v = src[j];
  f16x4 o = {(_Float16)v.x, (_Float16)v.y, (_Float16)v.z, (_Float16)v.w};
  *(f16x4*)&dst[(size_t)j * 4] = o;
}

// ---------------------------------------------------------------------------
// NT GEMM: C[M,N] = A[M,K] * Bw[N,K]^T (+bias). 128x128 tile, BK=64, 4 waves.
// EPI=0: qkv epilogue (scatter Q scaled, K, V^T).  EPI=1: plain f32 out.
// LDS rows are 128B; 16B chunks XOR-swizzled by (row&7), swizzle applied on
// the GLOBAL source address (global_load_lds dest must stay linear).
// ---------------------------------------------------------------------------
template <int EPI>
__global__ __launch_bounds__(256)
void gemm_nt(const _Float16* __restrict__ A, const _Float16* __restrict__ Bw,
             const float* __restrict__ bias,
             _Float16* __restrict__ qb, _Float16* __restrict__ kb,
             _Float16* __restrict__ vtb, float* __restrict__ outp) {
  __shared__ _Float16 As[128 * 64];
  __shared__ _Float16 Bs[128 * 64];
  const int tid = threadIdx.x;
  const int w = tid >> 6, lane = tid & 63;
  const int lr = lane & 15, lk = lane >> 4;
  const int m0 = blockIdx.y * 128, n0 = blockIdx.x * 128;
  const int wr = w >> 1, wc = w & 1;

  f32x4 acc[4][4] = {};
  const char* Ab = (const char*)(A + (size_t)m0 * TK);
  const char* Bb = (const char*)(Bw + (size_t)n0 * TK);

  for (int k0 = 0; k0 < TK; k0 += 64) {
#pragma unroll
    for (int c = 0; c < 4; ++c) {  // A tile: 128 rows x 128B
      int o = (w * 4 + c) * 1024 + lane * 16;
      int row = o >> 7, ch = (o >> 4) & 7;
      gload16(Ab + (size_t)row * (TK * 2) + k0 * 2 + ((ch ^ (row & 7)) << 4),
              (char*)As + (w * 4 + c) * 1024);
    }
#pragma unroll
    for (int c = 0; c < 4; ++c) {  // B tile
      int o = (w * 4 + c) * 1024 + lane * 16;
      int row = o >> 7, ch = (o >> 4) & 7;
      gload16(Bb + (size_t)row * (TK * 2) + k0 * 2 + ((ch ^ (row & 7)) << 4),
              (char*)Bs + (w * 4 + c) * 1024);
    }
    asm volatile("s_waitcnt vmcnt(0)" ::: "memory");
    __syncthreads();

#pragma unroll
    for (int kc = 0; kc < 2; ++kc) {
      f16x8 af[4], bf[4];
#pragma unroll
      for (int mi = 0; mi < 4; ++mi) {
        int row = wr * 64 + mi * 16 + lr;
        af[mi] = *(const f16x8*)&As[row * 64 + (((kc * 4 + lk) ^ (row & 7)) << 3)];
      }
#pragma unroll
      for (int ni = 0; ni < 4; ++ni) {
        int row = wc * 64 + ni * 16 + lr;
        bf[ni] = *(const f16x8*)&Bs[row * 64 + (((kc * 4 + lk) ^ (row & 7)) << 3)];
      }
#pragma unroll
      for (int mi = 0; mi < 4; ++mi)
#pragma unroll
        for (int ni = 0; ni < 4; ++ni)
          acc[mi][ni] = __builtin_amdgcn_mfma_f32_16x16x32_f16(af[mi], bf[ni],
                                                               acc[mi][ni], 0, 0, 0);
    }
    __syncthreads();
  }

  // epilogue: C layout col = lane&15, row = (lane>>4)*4 + r  [m89]
#pragma unroll
  for (int mi = 0; mi < 4; ++mi) {
#pragma unroll
    for (int ni = 0; ni < 4; ++ni) {
      const int col = n0 + wc * 64 + ni * 16 + lr;
#pragma unroll
      for (int r = 0; r < 4; ++r) {
        const int row = m0 + wr * 64 + mi * 16 + lk * 4 + r;
        float v = acc[mi][ni][r];
        if (EPI == 0) {
          v += bias[col];
          const int which = (col >= 2 * TE) ? 2 : (col >= TE ? 1 : 0);
          const int e = col - which * TE;
          const int h = e >> 6, d = e & 63;
          const int b = row >> 11, t = row & (TT - 1);
          const size_t hb = (size_t)(b * TH + h);
          if (which == 0)
            qb[(hb * TT + t) * TD + d] = (_Float16)(v * SCALE_LOG2E);
          else if (which == 1)
            kb[(hb * TT + t) * TD + d] = (_Float16)v;
          else
            vtb[(hb * TD + d) * TT + t] = (_Float16)v;  // V stored transposed
        } else {
          outp[(size_t)row * TE + col] = v;
        }
      }
    }
  }
}

// ---------------------------------------------------------------------------
// Causal flash attention. Grid (T/64, B*H). 4 waves; wave w owns 16 q-rows.
// Q pre-scaled by SCALE*log2e -> logits in base-2 domain, exp2 softmax.
// K tile [64s][64d], V^T tile [64d][64s] staged in LDS, XOR-swizzled.
// ---------------------------------------------------------------------------
__global__ __launch_bounds__(256)
void attn_kernel(const _Float16* __restrict__ qbuf, const _Float16* __restrict__ kbuf,
                 const _Float16* __restrict__ vtbuf, _Float16* __restrict__ ob) {
  __shared__ _Float16 Ks[64 * 64], Vs[64 * 64], Ps[4 * 16 * 64];
  const int tid = threadIdx.x, w = tid >> 6, lane = tid & 63;
  const int lr = lane & 15, lk = lane >> 4;
  const int t0 = ((int)gridDim.x - 1 - (int)blockIdx.x) * 64;  // heavy blocks first
  const int bh = blockIdx.y;
  const size_t hoff = (size_t)bh * (TT * TD);
  const _Float16* q = qbuf + hoff;    // [T][64]
  const _Float16* k = kbuf + hoff;    // [T][64]
  const _Float16* vt = vtbuf + hoff;  // [64][T]
  _Float16* Pw = Ps + w * (16 * 64);
  const int rb = w * 16;

  f16x8 qf[2];
#pragma unroll
  for (int kc = 0; kc < 2; ++kc)
    qf[kc] = *(const f16x8*)&q[(size_t)(t0 + rb + lr) * TD + kc * 32 + lk * 8];

  f32x4 of[4] = {};
  float mrun[4], lrun[4];
#pragma unroll
  for (int r = 0; r < 4; ++r) { mrun[r] = -1e30f; lrun[r] = 0.f; }

  const int nt = t0 / 64 + 1;
  for (int st = 0; st < nt; ++st) {
    const int s0 = st * 64;
#pragma unroll
    for (int c = 0; c < 2; ++c) {
      int o = (w * 2 + c) * 1024 + lane * 16;
      int row = o >> 7, ch = (o >> 4) & 7;
      gload16((const char*)(k + (size_t)s0 * TD) + (size_t)row * 128 +
                  ((ch ^ (row & 7)) << 4),
              (char*)Ks + (w * 2 + c) * 1024);
      gload16((const char*)(vt + s0) + (size_t)row * (TT * 2) +
                  ((ch ^ (row & 7)) << 4),
              (char*)Vs + (w * 2 + c) * 1024);
    }
    asm volatile("s_waitcnt vmcnt(0)" ::: "memory");
    __syncthreads();

    // S = Q K^T (already in log2 units)
    f32x4 sa[4] = {};
#pragma unroll
    for (int kc = 0; kc < 2; ++kc) {
#pragma unroll
      for (int ni = 0; ni < 4; ++ni) {
        int row = ni * 16 + lr;
        f16x8 kf = *(const f16x8*)&Ks[row * 64 + (((kc * 4 + lk) ^ (row & 7)) << 3)];
        sa[ni] = __builtin_amdgcn_mfma_f32_16x16x32_f16(qf[kc], kf, sa[ni], 0, 0, 0);
      }
    }
    if (st == nt - 1) {  // diagonal tile: causal mask
#pragma unroll
      for (int ni = 0; ni < 4; ++ni)
#pragma unroll
        for (int r = 0; r < 4; ++r)
          if (s0 + ni * 16 + lr > t0 + rb + lk * 4 + r) sa[ni][r] = -1e30f;
    }

    // wave-parallel row max over the 16 lanes sharing a row
    float mx[4];
#pragma unroll
    for (int r = 0; r < 4; ++r)
      mx[r] = fmaxf(fmaxf(sa[0][r], sa[1][r]), fmaxf(sa[2][r], sa[3][r]));
#pragma unroll
    for (int off = 1; off < 16; off <<= 1)
#pragma unroll
      for (int r = 0; r < 4; ++r) mx[r] = fmaxf(mx[r], __shfl_xor(mx[r], off));

    float al[4], rs[4];
#pragma unroll
    for (int r = 0; r < 4; ++r) {
      float mn = fmaxf(mrun[r], mx[r]);
      al[r] = __builtin_amdgcn_exp2f(mrun[r] - mn);
      mrun[r] = mn;
      rs[r] = 0.f;
    }
#pragma unroll
    for (int ni = 0; ni < 4; ++ni) {
#pragma unroll
      for (int r = 0; r < 4; ++r) {
        float p = __builtin_amdgcn_exp2f(sa[ni][r] - mrun[r]);
        rs[r] += p;
        int row = lk * 4 + r;  // P element (row, col=ni*16+lr), swizzled store
        Pw[row * 64 + (((ni * 2 + (lr >> 3)) ^ (row & 7)) << 3) + (lr & 7)] =
            (_Float16)p;
      }
    }
#pragma unroll
    for (int off = 1; off < 16; off <<= 1)
#pragma unroll
      for (int r = 0; r < 4; ++r) rs[r] += __shfl_xor(rs[r], off);
#pragma unroll
    for (int r = 0; r < 4; ++r) lrun[r] = lrun[r] * al[r] + rs[r];
#pragma unroll
    for (int nd = 0; nd < 4; ++nd)
#pragma unroll
      for (int r = 0; r < 4; ++r) of[nd][r] *= al[r];

    asm volatile("s_waitcnt lgkmcnt(0)" ::: "memory");  // P writes -> P reads

    // O += P V  (A = P from LDS, B = V^T tile)
#pragma unroll
    for (int kc = 0; kc < 2; ++kc) {
      f16x8 pa = *(const f16x8*)&Pw[lr * 64 + (((kc * 4 + lk) ^ (lr & 7)) << 3)];
#pragma unroll
      for (int nd = 0; nd < 4; ++nd) {
        int row = nd * 16 + lr;
        f16x8 vf = *(const f16x8*)&Vs[row * 64 + (((kc * 4 + lk) ^ (row & 7)) << 3)];
        of[nd] = __builtin_amdgcn_mfma_f32_16x16x32_f16(pa, vf, of[nd], 0, 0, 0);
      }
    }
    __syncthreads();
  }

  const int b = bh / TH, h = bh - b * TH;
#pragma unroll
  for (int nd = 0; nd < 4; ++nd) {
#pragma unroll
    for (int r = 0; r < 4; ++r) {
      int tg = t0 + rb + lk * 4 + r;
      int d = nd * 16 + lr;
      ob[(size_t)(b * TT + tg) * TE + h * TD + d] = (_Float16)(of[nd][r] / lrun[r]);
    }
  }
}

// ---------------------------------------------------------------------------
extern "C" void kernel_launch(void* const* d_in, const int* in_sizes, int n_in,
                              void* d_out, int out_size, void* d_ws, size_t ws_size,
                              hipStream_t stream) {
  const float* x    = (const float*)d_in[0];
  const float* wqkv = (const float*)d_in[1];
  const float* bqkv = (const float*)d_in[2];
  const float* wfin = (const float*)d_in[3];
  float* out = (float*)d_out;

  _Float16* xh  = (_Float16*)d_ws;          // [4096][768]
  _Float16* wqh = xh + (size_t)TM * TK;     // [2304][768]
  _Float16* wfh = wqh + (size_t)NQKV * TK;  // [768][768]
  _Float16* qb  = wfh + (size_t)TE * TE;    // [B,H,T,D] (pre-scaled)
  _Float16* kb  = qb + (size_t)TM * TE;     // [B,H,T,D]
  _Float16* vtb = kb + (size_t)TM * TE;     // [B,H,D,T]
  _Float16* ob  = vtb + (size_t)TM * TE;    // [4096][768] attn output

  cvt3<<<5376, 256, 0, stream>>>(x, wqkv, wfin, xh, wqh, wfh);
  gemm_nt<0><<<dim3(NQKV / 128, TM / 128), 256, 0, stream>>>(
      xh, wqh, bqkv, qb, kb, vtb, nullptr);
  attn_kernel<<<dim3(TT / 64, TB * TH), 256, 0, stream>>>(qb, kb, vtb, ob);
  gemm_nt<1><<<dim3(TE / 128, TM / 128), 256, 0, stream>>>(
      ob, wfh, nullptr, nullptr, nullptr, nullptr, out);
}

// Round 2
// 147.488 us; speedup vs baseline: 1.1693x; 1.1693x over previous
//
#include <hip/hip_runtime.h>
#include <cstdint>

typedef _Float16 f16x8 __attribute__((ext_vector_type(8)));
typedef _Float16 f16x4 __attribute__((ext_vector_type(4)));
typedef float    f32x4 __attribute__((ext_vector_type(4)));

static constexpr int TB = 2;
static constexpr int TT = 2048;
static constexpr int TE = 768;
static constexpr int TH = 12;
static constexpr int TD = 64;
static constexpr int TM = TB * TT;      // 4096 rows (B*T)
static constexpr int TK = TE;           // 768 (K for both GEMMs)
static constexpr int NQKV = 3 * TE;     // 2304

#define SCALE_LOG2E 0.18033688011112042f  /* (1/sqrt(64)) * log2(e) */

// async global->LDS, 16B per lane. LDS dest is wave-uniform base + lane*16.
__device__ __forceinline__ void gload16(const void* g, void* lds) {
  __builtin_amdgcn_global_load_lds(
      (__attribute__((address_space(1))) void*)(uintptr_t)g,
      (__attribute__((address_space(3))) void*)(uint32_t)(uintptr_t)lds, 16, 0, 0);
}

// ---------------------------------------------------------------------------
// f32 -> f16 convert for x, w_qkv, w_final (4 elems/thread)
// ---------------------------------------------------------------------------
__global__ void cvt3(const float* __restrict__ x, const float* __restrict__ wq,
                     const float* __restrict__ wf, _Float16* __restrict__ xh,
                     _Float16* __restrict__ wqh, _Float16* __restrict__ wfh) {
  const int NX = TM * TK / 4, NW = NQKV * TK / 4;
  int i = blockIdx.x * 256 + threadIdx.x;
  const float4* src; _Float16* dst; int j;
  if (i < NX)            { src = (const float4*)x;  dst = xh;  j = i; }
  else if (i < NX + NW)  { src = (const float4*)wq; dst = wqh; j = i - NX; }
  else                   { src = (const float4*)wf; dst = wfh; j = i - NX - NW; }
  float4 v = src[j];
  f16x4 o = {(_Float16)v.x, (_Float16)v.y, (_Float16)v.z, (_Float16)v.w};
  *(f16x4*)&dst[(size_t)j * 4] = o;
}

// ---------------------------------------------------------------------------
// NT GEMM: C[M,N] = A[M,K] * Bw[N,K]^T (+bias). 128x128 tile, BK=64, 4 waves.
// EPI=0: qkv epilogue (scatter Q scaled, K, V^T).  EPI=1: plain f32 out.
// ---------------------------------------------------------------------------
template <int EPI>
__global__ __launch_bounds__(256)
void gemm_nt(const _Float16* __restrict__ A, const _Float16* __restrict__ Bw,
             const float* __restrict__ bias,
             _Float16* __restrict__ qb, _Float16* __restrict__ kb,
             _Float16* __restrict__ vtb, float* __restrict__ outp) {
  __shared__ _Float16 As[128 * 64];
  __shared__ _Float16 Bs[128 * 64];
  const int tid = threadIdx.x;
  const int w = tid >> 6, lane = tid & 63;
  const int lr = lane & 15, lk = lane >> 4;
  const int m0 = blockIdx.y * 128, n0 = blockIdx.x * 128;
  const int wr = w >> 1, wc = w & 1;

  f32x4 acc[4][4] = {};
  const char* Ab = (const char*)(A + (size_t)m0 * TK);
  const char* Bb = (const char*)(Bw + (size_t)n0 * TK);

  for (int k0 = 0; k0 < TK; k0 += 64) {
#pragma unroll
    for (int c = 0; c < 4; ++c) {  // A tile: 128 rows x 128B
      int o = (w * 4 + c) * 1024 + lane * 16;
      int row = o >> 7, ch = (o >> 4) & 7;
      gload16(Ab + (size_t)row * (TK * 2) + k0 * 2 + ((ch ^ (row & 7)) << 4),
              (char*)As + (w * 4 + c) * 1024);
    }
#pragma unroll
    for (int c = 0; c < 4; ++c) {  // B tile
      int o = (w * 4 + c) * 1024 + lane * 16;
      int row = o >> 7, ch = (o >> 4) & 7;
      gload16(Bb + (size_t)row * (TK * 2) + k0 * 2 + ((ch ^ (row & 7)) << 4),
              (char*)Bs + (w * 4 + c) * 1024);
    }
    asm volatile("s_waitcnt vmcnt(0)" ::: "memory");
    __syncthreads();

#pragma unroll
    for (int kc = 0; kc < 2; ++kc) {
      f16x8 af[4], bf[4];
#pragma unroll
      for (int mi = 0; mi < 4; ++mi) {
        int row = wr * 64 + mi * 16 + lr;
        af[mi] = *(const f16x8*)&As[row * 64 + (((kc * 4 + lk) ^ (row & 7)) << 3)];
      }
#pragma unroll
      for (int ni = 0; ni < 4; ++ni) {
        int row = wc * 64 + ni * 16 + lr;
        bf[ni] = *(const f16x8*)&Bs[row * 64 + (((kc * 4 + lk) ^ (row & 7)) << 3)];
      }
      __builtin_amdgcn_s_setprio(1);
#pragma unroll
      for (int mi = 0; mi < 4; ++mi)
#pragma unroll
        for (int ni = 0; ni < 4; ++ni)
          acc[mi][ni] = __builtin_amdgcn_mfma_f32_16x16x32_f16(af[mi], bf[ni],
                                                               acc[mi][ni], 0, 0, 0);
      __builtin_amdgcn_s_setprio(0);
    }
    __syncthreads();
  }

  // epilogue: C layout col = lane&15, row = (lane>>4)*4 + r  [m89]
#pragma unroll
  for (int mi = 0; mi < 4; ++mi) {
#pragma unroll
    for (int ni = 0; ni < 4; ++ni) {
      const int col = n0 + wc * 64 + ni * 16 + lr;
#pragma unroll
      for (int r = 0; r < 4; ++r) {
        const int row = m0 + wr * 64 + mi * 16 + lk * 4 + r;
        float v = acc[mi][ni][r];
        if (EPI == 0) {
          v += bias[col];
          const int which = (col >= 2 * TE) ? 2 : (col >= TE ? 1 : 0);
          const int e = col - which * TE;
          const int h = e >> 6, d = e & 63;
          const int b = row >> 11, t = row & (TT - 1);
          const size_t hb = (size_t)(b * TH + h);
          if (which == 0)
            qb[(hb * TT + t) * TD + d] = (_Float16)(v * SCALE_LOG2E);
          else if (which == 1)
            kb[(hb * TT + t) * TD + d] = (_Float16)v;
          else
            vtb[(hb * TD + d) * TT + t] = (_Float16)v;  // V stored transposed
        } else {
          outp[(size_t)row * TE + col] = v;
        }
      }
    }
  }
}

// ---------------------------------------------------------------------------
// Causal flash attention. Grid (T/64, B*H). 4 waves; wave w owns 16 q-rows.
// Q pre-scaled by SCALE*log2e -> logits in base-2 domain, exp2 softmax.
// K tile [64s][64d], V^T tile [64d][64s], DOUBLE-BUFFERED in LDS, swizzled.
// Counted vmcnt + raw s_barrier: next tile's loads stay in flight across the
// barrier while the current tile computes (T3/T4 pattern).
// ---------------------------------------------------------------------------
__global__ __launch_bounds__(256)
void attn_kernel(const _Float16* __restrict__ qbuf, const _Float16* __restrict__ kbuf,
                 const _Float16* __restrict__ vtbuf, _Float16* __restrict__ ob) {
  __shared__ _Float16 Ks[2][64 * 64], Vs[2][64 * 64], Ps[4 * 16 * 64];
  const int tid = threadIdx.x, w = tid >> 6, lane = tid & 63;
  const int lr = lane & 15, lk = lane >> 4;
  const int t0 = ((int)gridDim.x - 1 - (int)blockIdx.x) * 64;  // heavy blocks first
  const int bh = blockIdx.y;
  const size_t hoff = (size_t)bh * (TT * TD);
  const _Float16* q = qbuf + hoff;    // [T][64]
  const _Float16* k = kbuf + hoff;    // [T][64]
  const _Float16* vt = vtbuf + hoff;  // [64][T]
  _Float16* Pw = Ps + w * (16 * 64);
  const int rb = w * 16;

  f16x8 qf[2];
#pragma unroll
  for (int kc = 0; kc < 2; ++kc)
    qf[kc] = *(const f16x8*)&q[(size_t)(t0 + rb + lr) * TD + kc * 32 + lk * 8];

  f32x4 of[4] = {};
  float mrun[4], lrun[4];
#pragma unroll
  for (int r = 0; r < 4; ++r) { mrun[r] = -1e30f; lrun[r] = 0.f; }

  const int nt = t0 / 64 + 1;

  // stage KV tile st into buffer buf (4 global_load_lds per wave)
  auto stage = [&](int st, int buf) {
    const int s0 = st * 64;
#pragma unroll
    for (int c = 0; c < 2; ++c) {
      int o = (w * 2 + c) * 1024 + lane * 16;
      int row = o >> 7, ch = (o >> 4) & 7;
      gload16((const char*)(k + (size_t)s0 * TD) + (size_t)row * 128 +
                  ((ch ^ (row & 7)) << 4),
              (char*)Ks[buf] + (w * 2 + c) * 1024);
      gload16((const char*)(vt + s0) + (size_t)row * (TT * 2) +
                  ((ch ^ (row & 7)) << 4),
              (char*)Vs[buf] + (w * 2 + c) * 1024);
    }
  };

  stage(0, 0);
  for (int st = 0; st < nt; ++st) {
    const int cur = st & 1;
    const int s0 = st * 64;
    if (st + 1 < nt) {
      stage(st + 1, cur ^ 1);  // 4 loads issued; they stay in flight
      asm volatile("s_waitcnt vmcnt(4)" ::: "memory");  // wait only cur's loads
    } else {
      asm volatile("s_waitcnt vmcnt(0)" ::: "memory");
    }
    __builtin_amdgcn_s_barrier();  // all waves' cur loads landed; NO full drain

    // S = Q K^T (already in log2 units)
    f32x4 sa[4] = {};
    __builtin_amdgcn_s_setprio(1);
#pragma unroll
    for (int kc = 0; kc < 2; ++kc) {
#pragma unroll
      for (int ni = 0; ni < 4; ++ni) {
        int row = ni * 16 + lr;
        f16x8 kf =
            *(const f16x8*)&Ks[cur][row * 64 + (((kc * 4 + lk) ^ (row & 7)) << 3)];
        sa[ni] = __builtin_amdgcn_mfma_f32_16x16x32_f16(qf[kc], kf, sa[ni], 0, 0, 0);
      }
    }
    __builtin_amdgcn_s_setprio(0);
    if (st == nt - 1) {  // diagonal tile: causal mask
#pragma unroll
      for (int ni = 0; ni < 4; ++ni)
#pragma unroll
        for (int r = 0; r < 4; ++r)
          if (s0 + ni * 16 + lr > t0 + rb + lk * 4 + r) sa[ni][r] = -1e30f;
    }

    // wave-parallel row max over the 16 lanes sharing a row
    float mx[4];
#pragma unroll
    for (int r = 0; r < 4; ++r)
      mx[r] = fmaxf(fmaxf(sa[0][r], sa[1][r]), fmaxf(sa[2][r], sa[3][r]));
#pragma unroll
    for (int off = 1; off < 16; off <<= 1)
#pragma unroll
      for (int r = 0; r < 4; ++r) mx[r] = fmaxf(mx[r], __shfl_xor(mx[r], off));

    float al[4], rs[4];
#pragma unroll
    for (int r = 0; r < 4; ++r) {
      float mn = fmaxf(mrun[r], mx[r]);
      al[r] = __builtin_amdgcn_exp2f(mrun[r] - mn);
      mrun[r] = mn;
      rs[r] = 0.f;
    }
#pragma unroll
    for (int ni = 0; ni < 4; ++ni) {
#pragma unroll
      for (int r = 0; r < 4; ++r) {
        float p = __builtin_amdgcn_exp2f(sa[ni][r] - mrun[r]);
        rs[r] += p;
        int row = lk * 4 + r;  // P element (row, col=ni*16+lr), swizzled store
        Pw[row * 64 + (((ni * 2 + (lr >> 3)) ^ (row & 7)) << 3) + (lr & 7)] =
            (_Float16)p;
      }
    }
#pragma unroll
    for (int off = 1; off < 16; off <<= 1)
#pragma unroll
      for (int r = 0; r < 4; ++r) rs[r] += __shfl_xor(rs[r], off);
#pragma unroll
    for (int r = 0; r < 4; ++r) lrun[r] = lrun[r] * al[r] + rs[r];
#pragma unroll
    for (int nd = 0; nd < 4; ++nd)
#pragma unroll
      for (int r = 0; r < 4; ++r) of[nd][r] *= al[r];

    asm volatile("s_waitcnt lgkmcnt(0)" ::: "memory");  // P writes -> P reads

    // O += P V  (A = P from LDS, B = V^T tile)
    __builtin_amdgcn_s_setprio(1);
#pragma unroll
    for (int kc = 0; kc < 2; ++kc) {
      f16x8 pa = *(const f16x8*)&Pw[lr * 64 + (((kc * 4 + lk) ^ (lr & 7)) << 3)];
#pragma unroll
      for (int nd = 0; nd < 4; ++nd) {
        int row = nd * 16 + lr;
        f16x8 vf =
            *(const f16x8*)&Vs[cur][row * 64 + (((kc * 4 + lk) ^ (row & 7)) << 3)];
        of[nd] = __builtin_amdgcn_mfma_f32_16x16x32_f16(pa, vf, of[nd], 0, 0, 0);
      }
    }
    __builtin_amdgcn_s_setprio(0);
    __builtin_amdgcn_s_barrier();  // protect cur buffer before it is restaged
  }

  const int b = bh / TH, h = bh - b * TH;
#pragma unroll
  for (int nd = 0; nd < 4; ++nd) {
#pragma unroll
    for (int r = 0; r < 4; ++r) {
      int tg = t0 + rb + lk * 4 + r;
      int d = nd * 16 + lr;
      ob[(size_t)(b * TT + tg) * TE + h * TD + d] = (_Float16)(of[nd][r] / lrun[r]);
    }
  }
}

// ---------------------------------------------------------------------------
extern "C" void kernel_launch(void* const* d_in, const int* in_sizes, int n_in,
                              void* d_out, int out_size, void* d_ws, size_t ws_size,
                              hipStream_t stream) {
  const float* x    = (const float*)d_in[0];
  const float* wqkv = (const float*)d_in[1];
  const float* bqkv = (const float*)d_in[2];
  const float* wfin = (const float*)d_in[3];
  float* out = (float*)d_out;

  _Float16* xh  = (_Float16*)d_ws;          // [4096][768]
  _Float16* wqh = xh + (size_t)TM * TK;     // [2304][768]
  _Float16* wfh = wqh + (size_t)NQKV * TK;  // [768][768]
  _Float16* qb  = wfh + (size_t)TE * TE;    // [B,H,T,D] (pre-scaled)
  _Float16* kb  = qb + (size_t)TM * TE;     // [B,H,T,D]
  _Float16* vtb = kb + (size_t)TM * TE;     // [B,H,D,T]
  _Float16* ob  = vtb + (size_t)TM * TE;    // [4096][768] attn output

  cvt3<<<5376, 256, 0, stream>>>(x, wqkv, wfin, xh, wqh, wfh);
  gemm_nt<0><<<dim3(NQKV / 128, TM / 128), 256, 0, stream>>>(
      xh, wqh, bqkv, qb, kb, vtb, nullptr);
  attn_kernel<<<dim3(TT / 64, TB * TH), 256, 0, stream>>>(qb, kb, vtb, ob);
  gemm_nt<1><<<dim3(TE / 128, TM / 128), 256, 0, stream>>>(
      ob, wfh, nullptr, nullptr, nullptr, nullptr, out);
}